// Round 5
// baseline (193.944 us; speedup 1.0000x reference)
//
#include <hip/hip_runtime.h>

// LocalEnergy R5: 64-row blocks, register-resident weights, LDS Xs tile with
// regular (conflict-free) GEMM1 reads; clustered ebuf gathers only in the
// vectorized X-build (R2-proven ~2M-conflict pattern).
// B=128, L=2048, E=16, H=128. Out = 128 f32.

typedef short bf16x8 __attribute__((ext_vector_type(8)));
typedef float f32x4  __attribute__((ext_vector_type(4)));

constexpr int Lc = 2048;

union FragU { uint4 u; bf16x8 v; unsigned short s[8]; };

__device__ __forceinline__ unsigned short f2bf(float f) {
    union { float f; unsigned u; } v; v.f = f;
    unsigned u = v.u;
    u = u + 0x7FFFu + ((u >> 16) & 1u);   // RTNE
    return (unsigned short)(u >> 16);
}

__device__ __forceinline__ unsigned pkbf(float a, float b) {
    unsigned ua = __float_as_uint(a) + 0x8000u;
    unsigned ub = __float_as_uint(b) + 0x8000u;
    return __builtin_amdgcn_perm(ub, ua, 0x07060302u);
}

// ws layout (bytes):
//   W2T[t] @ t*32768           : [col2=128][k=128] bf16 k-contig   (98304)
//   W1T[t] @ 98304 + t*16384   : [hid=128][k=64]   bf16 k-contig, emb rows only
//   EB     @ 147456            : [aa=20][16] bf16 (natural layout)
__global__ __launch_bounds__(256)
void prep_kernel(const float* __restrict__ W1_0, const float* __restrict__ W1_1,
                 const float* __restrict__ W1_2,
                 const float* __restrict__ W2_0, const float* __restrict__ W2_1,
                 const float* __restrict__ W2_2,
                 const float* __restrict__ emb, char* __restrict__ ws,
                 float* __restrict__ out)
{
    const int tid = blockIdx.x * 256 + threadIdx.x;
    const int np  = gridDim.x * 256;
    if (blockIdx.x == 0 && threadIdx.x < 128) out[threadIdx.x] = 0.0f;

    // W2^T: read coalesced (src row-major), write transposed
    unsigned short* d2 = (unsigned short*)ws;
    for (int i = tid; i < 3 * 16384; i += np) {
        int t = i >> 14, rr = i & 16383, k = rr >> 7, col = rr & 127;
        const float* W2 = (t == 0) ? W2_0 : (t == 1) ? W2_1 : W2_2;
        d2[(t << 14) + col * 128 + k] = f2bf(W2[rr]);
    }
    // W1^T (emb rows only; geom rows + b1 folded in energy epilogue)
    unsigned short* d1 = (unsigned short*)(ws + 98304);
    for (int i = tid; i < 3 * 8192; i += np) {
        int t = i >> 13, r = i & 8191, hid = r >> 6, k = r & 63;
        const int NE16 = (t == 0) ? 32 : (t == 1) ? 48 : 64;
        const int NG   = (t == 2) ? 2 : 1;
        const float* W1 = (t == 0) ? W1_0 : (t == 1) ? W1_1 : W1_2;
        d1[i] = (k < NE16) ? f2bf(W1[(NG + k) * 128 + hid]) : (unsigned short)0;
    }
    // emb bf16, natural [20][16]
    unsigned short* eb = (unsigned short*)(ws + 147456);
    for (int i = tid; i < 320; i += np) eb[i] = f2bf(emb[i]);
}

struct SMem {
    unsigned short H1s[64 * 136];   // 17408 B
    unsigned short Xs[64 * 72];     //  9216 B (SA<=72 shorts; rows 144B/80B, 16B-aligned)
    float  Rbuf[204];               // 67 rows x 3
    float  geomb[128];              // [2][64]
    int    seqb[68];
    unsigned short ebuf[320];       // [20][16] bf16
    float  part[4];
};

template<int TYPE>
__device__ __forceinline__ void body(
    SMem* sm,
    const float* __restrict__ R, const int* __restrict__ seq,
    const char* __restrict__ ws,
    const float* __restrict__ W1, const float* __restrict__ b1,
    const float* __restrict__ b2, const float* __restrict__ w3,
    const float* __restrict__ b3, float* __restrict__ out)
{
    constexpr int NEMB  = (TYPE == 0) ? 2 : (TYPE == 1) ? 3 : 4;
    constexpr int NG    = (TYPE == 2) ? 2 : 1;
    constexpr int KS1   = (TYPE == 0) ? 1 : 2;
    constexpr int SA    = (TYPE == 0) ? 40 : 72;   // K+8 shorts; K=32 or 64
    constexpr int JC    = KS1 * 4;                 // 16B chunks per row
    constexpr int ROWSB = Lc - 1 - TYPE;
    constexpr int SHs   = 136;

    const int tid = threadIdx.x;
    const int b   = blockIdx.y;
    const int i0  = blockIdx.x * 64;
    const int lane = tid & 63, wv = tid >> 6;
    const int q = lane >> 4, c = lane & 15;

    const unsigned short* w1t = (const unsigned short*)(ws + 98304 + TYPE * 16384);
    const unsigned short* w2t = (const unsigned short*)(ws + TYPE * 32768);

    // ---- GEMM1 A-frags (W1t, L2-hot) ----
    FragU A1[2][2];
#pragma unroll
    for (int mt = 0; mt < 2; ++mt)
#pragma unroll
        for (int ks = 0; ks < KS1; ++ks)
            A1[mt][ks].u = *(const uint4*)&w1t[(wv * 32 + mt * 16 + c) * 64 + ks * 32 + q * 8];

    // ---- stage R / seq / ebuf ----
    for (int t = tid; t < 201; t += 256) {
        int lr = t / 3, comp = t - lr * 3;
        int row = min(i0 + lr, Lc - 1);
        sm->Rbuf[t] = R[((size_t)b * Lc + row) * 3 + comp];
    }
    for (int t = tid; t < 67; t += 256)
        sm->seqb[t] = seq[b * Lc + min(i0 + t, Lc - 1)];
    {
        const uint4* se = (const uint4*)(ws + 147456);
        for (int t = tid; t < 40; t += 256) ((uint4*)sm->ebuf)[t] = se[t];
    }
    __syncthreads();

    // ---- geometry (threads 0..63) ----
    if (tid < 64) {
        const float* p0 = &sm->Rbuf[tid * 3];
        float ax = p0[3] - p0[0], ay = p0[4] - p0[1], az = p0[5] - p0[2];
        float g0 = 0.f, g1 = 0.f;
        if (TYPE == 0) {
            g0 = sqrtf(ax * ax + ay * ay + az * az);
        } else if (TYPE == 1) {
            float bx = p0[6] - p0[3], by = p0[7] - p0[4], bz = p0[8] - p0[5];
            float duv = -(ax * bx + ay * by + az * bz);
            float na2 = ax * ax + ay * ay + az * az;
            float nb2 = bx * bx + by * by + bz * bz;
            float cosv = duv / sqrtf(na2 * nb2);
            g0 = fminf(fmaxf(cosv, -1.0f), 1.0f);
        } else {
            float bx = p0[6] - p0[3], by = p0[7] - p0[4], bz = p0[8] - p0[5];
            float cx = p0[9] - p0[6], cy = p0[10] - p0[7], cz = p0[11] - p0[8];
            float n1x = ay * bz - az * by, n1y = az * bx - ax * bz, n1z = ax * by - ay * bx;
            float n2x = by * cz - bz * cy, n2y = bz * cx - bx * cz, n2z = bx * cy - by * cx;
            float binv = 1.0f / sqrtf(bx * bx + by * by + bz * bz);
            float ux = bx * binv, uy = by * binv, uz = bz * binv;
            float m1x = n1y * uz - n1z * uy, m1y = n1z * ux - n1x * uz, m1z = n1x * uy - n1y * ux;
            float yv = m1x * n2x + m1y * n2y + m1z * n2z;
            float xv = n1x * n2x + n1y * n2y + n1z * n2z;
            float inv = 1.0f / sqrtf(xv * xv + yv * yv);
            g0 = yv * inv; g1 = xv * inv;
        }
        sm->geomb[tid] = g0;
        sm->geomb[64 + tid] = g1;
    }
    // ---- X-build: vectorized 16B embedding-chunk copies (clustered gather) ----
    for (int idx = tid; idx < 64 * JC; idx += 256) {
        int r = idx / JC, jc = idx - r * JC;
        uint4 v = make_uint4(0u, 0u, 0u, 0u);
        if (jc < NEMB * 2) {
            int j = jc >> 1, h = jc & 1;
            v = *(const uint4*)&sm->ebuf[sm->seqb[r + j] * 16 + h * 8];
        }
        *(uint4*)&sm->Xs[r * SA + jc * 8] = v;
    }
    __syncthreads();

    // ---- GEMM1 (swapped): acc1[mt][nt] = D[hid][row]; Xs read conflict-free ----
    f32x4 acc1[2][4];
#pragma unroll
    for (int mt = 0; mt < 2; ++mt)
#pragma unroll
        for (int nt = 0; nt < 4; ++nt)
            acc1[mt][nt] = (f32x4){0.f, 0.f, 0.f, 0.f};

#pragma unroll
    for (int ks = 0; ks < KS1; ++ks)
#pragma unroll
        for (int nt = 0; nt < 4; ++nt) {
            bf16x8 bb = *(const bf16x8*)&sm->Xs[(nt * 16 + c) * SA + ks * 32 + q * 8];
            acc1[0][nt] = __builtin_amdgcn_mfma_f32_16x16x32_bf16(A1[0][ks].v, bb, acc1[0][nt], 0, 0, 0);
            acc1[1][nt] = __builtin_amdgcn_mfma_f32_16x16x32_bf16(A1[1][ks].v, bb, acc1[1][nt], 0, 0, 0);
        }

    // ---- epilogue constants + W2 B-frags (L2-hot; overlaps MFMA drain) ----
    float b1v[8], g0v[8], g1v[8];
#pragma unroll
    for (int mt = 0; mt < 2; ++mt)
#pragma unroll
        for (int rg = 0; rg < 4; ++rg) {
            int hid = wv * 32 + mt * 16 + q * 4 + rg;
            b1v[mt * 4 + rg] = b1[hid];
            g0v[mt * 4 + rg] = W1[hid];
            if (NG == 2) g1v[mt * 4 + rg] = W1[128 + hid];
        }
    FragU B2[2][4];
#pragma unroll
    for (int nt = 0; nt < 2; ++nt)
#pragma unroll
        for (int ks = 0; ks < 4; ++ks)
            B2[nt][ks].u = *(const uint4*)&w2t[(wv * 32 + nt * 16 + c) * 128 + ks * 32 + q * 8];
    float b2v[2], w3v[2];
#pragma unroll
    for (int nt = 0; nt < 2; ++nt) {
        int col2 = wv * 32 + nt * 16 + c;
        b2v[nt] = b2[col2]; w3v[nt] = w3[col2];
    }

    // ---- H1 = relu(acc1 + geom*w1g + b1) -> H1s (packed 8B writes) ----
    float gm0[4], gm1[4];
#pragma unroll
    for (int nt = 0; nt < 4; ++nt) {
        gm0[nt] = sm->geomb[nt * 16 + c];
        if (NG == 2) gm1[nt] = sm->geomb[64 + nt * 16 + c];
    }
#pragma unroll
    for (int mt = 0; mt < 2; ++mt)
#pragma unroll
        for (int nt = 0; nt < 4; ++nt) {
            float v0 = acc1[mt][nt][0] + gm0[nt] * g0v[mt * 4 + 0] + b1v[mt * 4 + 0];
            float v1 = acc1[mt][nt][1] + gm0[nt] * g0v[mt * 4 + 1] + b1v[mt * 4 + 1];
            float v2 = acc1[mt][nt][2] + gm0[nt] * g0v[mt * 4 + 2] + b1v[mt * 4 + 2];
            float v3 = acc1[mt][nt][3] + gm0[nt] * g0v[mt * 4 + 3] + b1v[mt * 4 + 3];
            if (NG == 2) {
                v0 += gm1[nt] * g1v[mt * 4 + 0];
                v1 += gm1[nt] * g1v[mt * 4 + 1];
                v2 += gm1[nt] * g1v[mt * 4 + 2];
                v3 += gm1[nt] * g1v[mt * 4 + 3];
            }
            v0 = fmaxf(v0, 0.f); v1 = fmaxf(v1, 0.f);
            v2 = fmaxf(v2, 0.f); v3 = fmaxf(v3, 0.f);
            uint2 pk;
            pk.x = pkbf(v0, v1);
            pk.y = pkbf(v2, v3);
            *(uint2*)&sm->H1s[(nt * 16 + c) * SHs + wv * 32 + mt * 16 + q * 4] = pk;
        }
    __syncthreads();

    // ---- GEMM2: acc2[mt][nt] = D[row][col2] ----
    f32x4 acc2[4][2];
#pragma unroll
    for (int mt = 0; mt < 4; ++mt)
#pragma unroll
        for (int nt = 0; nt < 2; ++nt)
            acc2[mt][nt] = (f32x4){0.f, 0.f, 0.f, 0.f};

#pragma unroll
    for (int ks = 0; ks < 4; ++ks)
#pragma unroll
        for (int mt = 0; mt < 4; ++mt) {
            bf16x8 aa = *(const bf16x8*)&sm->H1s[(mt * 16 + c) * SHs + ks * 32 + q * 8];
            acc2[mt][0] = __builtin_amdgcn_mfma_f32_16x16x32_bf16(aa, B2[0][ks].v, acc2[mt][0], 0, 0, 0);
            acc2[mt][1] = __builtin_amdgcn_mfma_f32_16x16x32_bf16(aa, B2[1][ks].v, acc2[mt][1], 0, 0, 0);
        }

    // ---- epilogue: sum relu(h2+b2)*w3 over this wave's col2 chunk ----
    float p = 0.0f;
#pragma unroll
    for (int mt = 0; mt < 4; ++mt)
#pragma unroll
        for (int rg = 0; rg < 4; ++rg) {
            int m = mt * 16 + q * 4 + rg;
            if (i0 + m < ROWSB) {
                p += fmaxf(acc2[mt][0][rg] + b2v[0], 0.f) * w3v[0];
                p += fmaxf(acc2[mt][1][rg] + b2v[1], 0.f) * w3v[1];
            }
        }
#pragma unroll
    for (int off = 32; off > 0; off >>= 1)
        p += __shfl_down(p, off);
    if (lane == 0) sm->part[wv] = p;
    __syncthreads();
    if (tid == 0) {
        int vc = min(ROWSB - i0, 64);
        atomicAdd(&out[b], sm->part[0] + sm->part[1] + sm->part[2] + sm->part[3]
                           + b3[0] * (float)vc);
    }
}

__global__ __launch_bounds__(256, 5)
void energy_kernel(const float* __restrict__ R, const int* __restrict__ seq,
                   const char* __restrict__ ws,
                   const float* W1_0, const float* b1_0,
                   const float* W1_1, const float* b1_1,
                   const float* W1_2, const float* b1_2,
                   const float* b2_0, const float* b2_1, const float* b2_2,
                   const float* w3_0, const float* w3_1, const float* w3_2,
                   const float* b3_0, const float* b3_1, const float* b3_2,
                   float* out)
{
    __shared__ SMem sm;
    if (blockIdx.z == 0)
        body<0>(&sm, R, seq, ws, W1_0, b1_0, b2_0, w3_0, b3_0, out);
    else if (blockIdx.z == 1)
        body<1>(&sm, R, seq, ws, W1_1, b1_1, b2_1, w3_1, b3_1, out);
    else
        body<2>(&sm, R, seq, ws, W1_2, b1_2, b2_2, w3_2, b3_2, out);
}

extern "C" void kernel_launch(void* const* d_in, const int* in_sizes, int n_in,
                              void* d_out, int out_size, void* d_ws, size_t ws_size,
                              hipStream_t stream) {
    const float* R   = (const float*)d_in[0];
    const int*   seq = (const int*)d_in[1];
    const float* emb = (const float*)d_in[2];
    float* out = (float*)d_out;
    char*  ws  = (char*)d_ws;

    prep_kernel<<<dim3(96), dim3(256), 0, stream>>>(
        (const float*)d_in[3], (const float*)d_in[9], (const float*)d_in[15],
        (const float*)d_in[5], (const float*)d_in[11], (const float*)d_in[17],
        emb, ws, out);

    dim3 grid(32, 128, 3), block(256);
    energy_kernel<<<grid, block, 0, stream>>>(
        R, seq, ws,
        (const float*)d_in[3],  (const float*)d_in[4],
        (const float*)d_in[9],  (const float*)d_in[10],
        (const float*)d_in[15], (const float*)d_in[16],
        (const float*)d_in[6],  (const float*)d_in[12], (const float*)d_in[18],
        (const float*)d_in[7],  (const float*)d_in[13], (const float*)d_in[19],
        (const float*)d_in[8],  (const float*)d_in[14], (const float*)d_in[20],
        out);
}

// Round 6
// 187.265 us; speedup vs baseline: 1.0357x; 1.0357x over previous
//
#include <hip/hip_runtime.h>

// LocalEnergy R6: all 3 energy types fused in one block; shared Xs tile with
// geometry+bias folded into MFMA K-slots (k0..4 header); 64 rows/block;
// weights register-resident from prepped bf16 ws. B=128, L=2048, H=128.
//
// Xs row (K=96): [len, cos_t, sin_p, cos_p, 1.0, 0 x11, e(r), e(r+1), e(r+2), e(r+3)]
// W1T[t] rows select per-type features (zeros elsewhere); t0/t1 use ks=0,1; t2 ks=0..2.

typedef short bf16x8 __attribute__((ext_vector_type(8)));
typedef float f32x4  __attribute__((ext_vector_type(4)));

constexpr int Lc  = 2048;
constexpr int SXs = 104;   // Xs stride (shorts) = 208 B
constexpr int SHs = 136;   // H1s stride (shorts) = 272 B

union FragU { uint4 u; bf16x8 v; };

__device__ __forceinline__ unsigned short f2bf(float f) {
    union { float f; unsigned u; } v; v.f = f;
    unsigned u = v.u;
    u = u + 0x7FFFu + ((u >> 16) & 1u);   // RTNE
    return (unsigned short)(u >> 16);
}

__device__ __forceinline__ unsigned pkbf(float a, float b) {
    unsigned ua = __float_as_uint(a) + 0x8000u;
    unsigned ub = __float_as_uint(b) + 0x8000u;
    return __builtin_amdgcn_perm(ub, ua, 0x07060302u);  // [lo=bf(a), hi=bf(b)]
}

// ws layout (bytes):
//   W2T[t] @ t*32768          : [col2=128][k=128] bf16 k-contig      (98304)
//   W1T[t] @ 98304 + t*24576  : [hid=128][k=96]   bf16 k-contig      (73728)
//   EB     @ 172032           : [aa=20][16] bf16                     (640)
__global__ __launch_bounds__(256)
void prep_kernel(const float* __restrict__ W1_0, const float* __restrict__ b1_0,
                 const float* __restrict__ W1_1, const float* __restrict__ b1_1,
                 const float* __restrict__ W1_2, const float* __restrict__ b1_2,
                 const float* __restrict__ W2_0, const float* __restrict__ W2_1,
                 const float* __restrict__ W2_2,
                 const float* __restrict__ emb, char* __restrict__ ws,
                 float* __restrict__ out)
{
    const int tid = blockIdx.x * 256 + threadIdx.x;
    const int np  = gridDim.x * 256;
    if (blockIdx.x == 0 && threadIdx.x < 128) out[threadIdx.x] = 0.0f;

    // W2^T (read coalesced, write transposed)
    unsigned short* d2 = (unsigned short*)ws;
    for (int i = tid; i < 3 * 16384; i += np) {
        int t = i >> 14, rr = i & 16383, k = rr >> 7, col = rr & 127;
        const float* W2 = (t == 0) ? W2_0 : (t == 1) ? W2_1 : W2_2;
        d2[(t << 14) + col * 128 + k] = f2bf(W2[rr]);
    }
    // W1^T with header slots: k0=len-row(t0), k1=cos-row(t1), k2/k3=sin/cos rows(t2),
    // k4=b1, k16.. = embedding rows
    unsigned short* d1 = (unsigned short*)(ws + 98304);
    for (int i = tid; i < 3 * 12288; i += np) {
        int t = i / 12288, rr = i - t * 12288, hid = rr / 96, k = rr - hid * 96;
        const int NE16 = (t == 0) ? 32 : (t == 1) ? 48 : 64;
        const int NG   = (t == 2) ? 2 : 1;
        const float* W1 = (t == 0) ? W1_0 : (t == 1) ? W1_1 : W1_2;
        const float* b1 = (t == 0) ? b1_0 : (t == 1) ? b1_1 : b1_2;
        float v = 0.0f;
        if (k >= 16) {
            int j = k - 16;
            if (j < NE16) v = W1[(NG + j) * 128 + hid];
        } else if (k == 4) v = b1[hid];
        else if (t == 0 && k == 0) v = W1_0[hid];
        else if (t == 1 && k == 1) v = W1_1[hid];
        else if (t == 2 && k == 2) v = W1_2[hid];
        else if (t == 2 && k == 3) v = W1_2[128 + hid];
        d1[i] = f2bf(v);
    }
    unsigned short* eb = (unsigned short*)(ws + 172032);
    for (int i = tid; i < 320; i += np) eb[i] = f2bf(emb[i]);
}

struct SMem {
    unsigned short H1s[64 * SHs];   // 34816 B
    unsigned short Xs[64 * SXs];    // 13312 B
    float  Rbuf[204];               // 67 rows x 3
    int    seqb[68];                // byte offsets into ebuf
    unsigned short ebuf[320];
    float  part[4];
};

template<int T>
__device__ __forceinline__ void process_type(
    SMem& sm, const char* __restrict__ ws,
    const float* __restrict__ b2, const float* __restrict__ w3,
    int i0, int wv, int q, int c, f32x4& p4)
{
    constexpr int KS    = (T == 2) ? 3 : 2;
    constexpr int ROWSB = Lc - 1 - T;

    const unsigned short* w1t = (const unsigned short*)(ws + 98304 + T * 24576);
    const unsigned short* w2t = (const unsigned short*)(ws + T * 32768);

    // A-frags (W1T) + B2 frags + consts (L2-hot)
    FragU A1[2][3];
#pragma unroll
    for (int mt = 0; mt < 2; ++mt)
#pragma unroll
        for (int ks = 0; ks < KS; ++ks)
            A1[mt][ks].u = *(const uint4*)&w1t[(wv * 32 + mt * 16 + c) * 96 + ks * 32 + q * 8];
    FragU B2[2][4];
#pragma unroll
    for (int nt = 0; nt < 2; ++nt)
#pragma unroll
        for (int ks = 0; ks < 4; ++ks)
            B2[nt][ks].u = *(const uint4*)&w2t[(wv * 32 + nt * 16 + c) * 128 + ks * 32 + q * 8];
    float b2v[2], w3v[2];
#pragma unroll
    for (int nt = 0; nt < 2; ++nt) {
        int col2 = wv * 32 + nt * 16 + c;
        b2v[nt] = b2[col2]; w3v[nt] = w3[col2];
    }

    // GEMM1 (swapped): D[hid][row]; geometry+bias arrive via header K-slots
    f32x4 acc1[2][4];
#pragma unroll
    for (int mt = 0; mt < 2; ++mt)
#pragma unroll
        for (int nt = 0; nt < 4; ++nt)
            acc1[mt][nt] = (f32x4){0.f, 0.f, 0.f, 0.f};
#pragma unroll
    for (int ks = 0; ks < KS; ++ks)
#pragma unroll
        for (int nt = 0; nt < 4; ++nt) {
            bf16x8 bb = *(const bf16x8*)&sm.Xs[(nt * 16 + c) * SXs + ks * 32 + q * 8];
            acc1[0][nt] = __builtin_amdgcn_mfma_f32_16x16x32_bf16(A1[0][ks].v, bb, acc1[0][nt], 0, 0, 0);
            acc1[1][nt] = __builtin_amdgcn_mfma_f32_16x16x32_bf16(A1[1][ks].v, bb, acc1[1][nt], 0, 0, 0);
        }

    // H1 = relu(acc1) -> H1s (packed 8B writes; hid contiguous in reg dim)
    const f32x4 z4 = (f32x4){0.f, 0.f, 0.f, 0.f};
#pragma unroll
    for (int mt = 0; mt < 2; ++mt)
#pragma unroll
        for (int nt = 0; nt < 4; ++nt) {
            f32x4 v = __builtin_elementwise_max(acc1[mt][nt], z4);
            uint2 pk;
            pk.x = pkbf(v[0], v[1]);
            pk.y = pkbf(v[2], v[3]);
            *(uint2*)&sm.H1s[(nt * 16 + c) * SHs + wv * 32 + mt * 16 + q * 4] = pk;
        }
    __syncthreads();

    // GEMM2: D[row][col2], W2 frags from registers
    f32x4 acc2[4][2];
#pragma unroll
    for (int mt = 0; mt < 4; ++mt)
#pragma unroll
        for (int nt = 0; nt < 2; ++nt)
            acc2[mt][nt] = (f32x4){0.f, 0.f, 0.f, 0.f};
#pragma unroll
    for (int ks = 0; ks < 4; ++ks)
#pragma unroll
        for (int mt = 0; mt < 4; ++mt) {
            bf16x8 aa = *(const bf16x8*)&sm.H1s[(mt * 16 + c) * SHs + ks * 32 + q * 8];
            acc2[mt][0] = __builtin_amdgcn_mfma_f32_16x16x32_bf16(aa, B2[0][ks].v, acc2[mt][0], 0, 0, 0);
            acc2[mt][1] = __builtin_amdgcn_mfma_f32_16x16x32_bf16(aa, B2[1][ks].v, acc2[mt][1], 0, 0, 0);
        }

    // epilogue: p += relu(h2 + b2) * w3 (vectorized; prefix row-mask fast path)
#pragma unroll
    for (int mt = 0; mt < 4; ++mt) {
        int mbase = mt * 16 + q * 4;
        if (i0 + mbase + 3 < ROWSB) {
#pragma unroll
            for (int nt = 0; nt < 2; ++nt) {
                f32x4 v = acc2[mt][nt] + b2v[nt];
                v = __builtin_elementwise_max(v, z4);
                p4 += v * w3v[nt];
            }
        } else {
#pragma unroll
            for (int rg = 0; rg < 4; ++rg)
                if (i0 + mbase + rg < ROWSB) {
                    p4[rg] += fmaxf(acc2[mt][0][rg] + b2v[0], 0.f) * w3v[0];
                    p4[rg] += fmaxf(acc2[mt][1][rg] + b2v[1], 0.f) * w3v[1];
                }
        }
    }
    __syncthreads();   // WAR: H1s reused by next type
}

__global__ __launch_bounds__(256, 3)
void energy_kernel(const float* __restrict__ R, const int* __restrict__ seq,
                   const char* __restrict__ ws,
                   const float* b2_0, const float* b2_1, const float* b2_2,
                   const float* w3_0, const float* w3_1, const float* w3_2,
                   const float* b3_0, const float* b3_1, const float* b3_2,
                   float* __restrict__ out)
{
    __shared__ SMem sm;
    const int tid = threadIdx.x;
    const int b   = blockIdx.y;
    const int i0  = blockIdx.x * 64;
    const int lane = tid & 63, wv = tid >> 6;
    const int q = lane >> 4, c = lane & 15;

    // ---- stage R / seq (as ebuf byte offsets) / ebuf ----
    for (int t = tid; t < 201; t += 256) {
        int lr = t / 3, comp = t - lr * 3;
        int row = min(i0 + lr, Lc - 1);
        sm.Rbuf[t] = R[((size_t)b * Lc + row) * 3 + comp];
    }
    for (int t = tid; t < 67; t += 256)
        sm.seqb[t] = seq[b * Lc + min(i0 + t, Lc - 1)] << 5;   // *32 bytes/row
    {
        const uint4* se = (const uint4*)(ws + 172032);
        for (int t = tid; t < 40; t += 256) ((uint4*)sm.ebuf)[t] = se[t];
    }
    __syncthreads();

    // ---- geometry -> Xs header (one pass, all 3 types share d-vectors) ----
    if (tid < 64) {
        const float* p0 = &sm.Rbuf[tid * 3];
        float ax = p0[3] - p0[0], ay = p0[4] - p0[1], az = p0[5] - p0[2];
        float bx = p0[6] - p0[3], by = p0[7] - p0[4], bz = p0[8] - p0[5];
        float cx = p0[9] - p0[6], cy = p0[10] - p0[7], cz = p0[11] - p0[8];
        float na2 = ax * ax + ay * ay + az * az;
        float len = sqrtf(na2);
        float nb2 = bx * bx + by * by + bz * bz;
        float duv = -(ax * bx + ay * by + az * bz);
        float cost = fminf(fmaxf(duv / sqrtf(na2 * nb2), -1.0f), 1.0f);
        float n1x = ay * bz - az * by, n1y = az * bx - ax * bz, n1z = ax * by - ay * bx;
        float n2x = by * cz - bz * cy, n2y = bz * cx - bx * cz, n2z = bx * cy - by * cx;
        float binv = 1.0f / sqrtf(nb2);
        float ux = bx * binv, uy = by * binv, uz = bz * binv;
        float m1x = n1y * uz - n1z * uy, m1y = n1z * ux - n1x * uz, m1z = n1x * uy - n1y * ux;
        float yv = m1x * n2x + m1y * n2y + m1z * n2z;
        float xv = n1x * n2x + n1y * n2y + n1z * n2z;
        float inv = 1.0f / sqrtf(xv * xv + yv * yv);
        float sinp = yv * inv, cosp = xv * inv;
        uint4 h;
        h.x = pkbf(len, cost);
        h.y = pkbf(sinp, cosp);
        h.z = 0x00003F80u;          // [1.0, 0]
        h.w = 0u;
        *(uint4*)&sm.Xs[tid * SXs]     = h;
        *(uint4*)&sm.Xs[tid * SXs + 8] = make_uint4(0u, 0u, 0u, 0u);
    }
    // ---- e-part build: 16B embedding chunks, k16..79 ----
    for (int idx = tid; idx < 512; idx += 256) {
        int r = idx >> 3, jc = idx & 7;
        uint4 v = *(const uint4*)((const char*)sm.ebuf + sm.seqb[r + (jc >> 1)] + (jc & 1) * 16);
        *(uint4*)&sm.Xs[r * SXs + 16 + jc * 8] = v;
    }
    __syncthreads();

    // ---- three fused type passes ----
    f32x4 p4 = (f32x4){0.f, 0.f, 0.f, 0.f};
    process_type<0>(sm, ws, b2_0, w3_0, i0, wv, q, c, p4);
    process_type<1>(sm, ws, b2_1, w3_1, i0, wv, q, c, p4);
    process_type<2>(sm, ws, b2_2, w3_2, i0, wv, q, c, p4);

    float p = p4[0] + p4[1] + p4[2] + p4[3];
#pragma unroll
    for (int off = 32; off > 0; off >>= 1)
        p += __shfl_down(p, off);
    if (lane == 0) sm.part[wv] = p;
    __syncthreads();
    if (tid == 0) {
        float tot = sm.part[0] + sm.part[1] + sm.part[2] + sm.part[3];
        tot += b3_0[0] * (float)min(Lc - 1 - i0, 64);
        tot += b3_1[0] * (float)min(Lc - 2 - i0, 64);
        tot += b3_2[0] * (float)min(Lc - 3 - i0, 64);
        atomicAdd(&out[b], tot);
    }
}

extern "C" void kernel_launch(void* const* d_in, const int* in_sizes, int n_in,
                              void* d_out, int out_size, void* d_ws, size_t ws_size,
                              hipStream_t stream) {
    const float* R   = (const float*)d_in[0];
    const int*   seq = (const int*)d_in[1];
    const float* emb = (const float*)d_in[2];
    float* out = (float*)d_out;
    char*  ws  = (char*)d_ws;

    prep_kernel<<<dim3(96), dim3(256), 0, stream>>>(
        (const float*)d_in[3],  (const float*)d_in[4],
        (const float*)d_in[9],  (const float*)d_in[10],
        (const float*)d_in[15], (const float*)d_in[16],
        (const float*)d_in[5],  (const float*)d_in[11], (const float*)d_in[17],
        emb, ws, out);

    dim3 grid(32, 128), block(256);
    energy_kernel<<<grid, block, 0, stream>>>(
        R, seq, ws,
        (const float*)d_in[6],  (const float*)d_in[12], (const float*)d_in[18],
        (const float*)d_in[7],  (const float*)d_in[13], (const float*)d_in[19],
        (const float*)d_in[8],  (const float*)d_in[14], (const float*)d_in[20],
        out);
}

// Round 7
// 167.680 us; speedup vs baseline: 1.1566x; 1.1168x over previous
//
#include <hip/hip_runtime.h>

// LocalEnergy R7: 128-row tiles, one type per block (z), single fused launch.
// Geometry+bias folded into MFMA K-slots via pre-packed bf16 header; direct
// ebuf gather for GEMM1 B-frags (lowest-conflict variant, R3-measured);
// weights register-resident from prepped bf16 ws; coalesced prep writes.
// B=128, L=2048, E=16, H=128. Out = 128 f32.
//
// X row (K=96, virtual): [len, cos_t, sin_p, cos_p, 1.0, 0 x11, e(r..r+3)]
// W1T[t] selects per-type features (zeros elsewhere); KS: t0=2, t1=2, t2=3.

typedef short bf16x8 __attribute__((ext_vector_type(8)));
typedef float f32x4  __attribute__((ext_vector_type(4)));

constexpr int Lc  = 2048;
constexpr int SHs = 136;   // H1s stride (shorts) = 272 B

union FragU { uint4 u; bf16x8 v; };

__device__ __forceinline__ unsigned short f2bf(float f) {
    union { float f; unsigned u; } v; v.f = f;
    unsigned u = v.u;
    u = u + 0x7FFFu + ((u >> 16) & 1u);   // RTNE
    return (unsigned short)(u >> 16);
}

__device__ __forceinline__ unsigned pkbf(float a, float b) {
    unsigned ua = __float_as_uint(a) + 0x8000u;
    unsigned ub = __float_as_uint(b) + 0x8000u;
    return __builtin_amdgcn_perm(ub, ua, 0x07060302u);  // [lo=bf(a), hi=bf(b)]
}

// ws layout (bytes):
//   W2T[t] @ t*32768          : [col2=128][k=128] bf16 k-contig      (98304)
//   W1T[t] @ 98304 + t*24576  : [hid=128][k=96]   bf16 k-contig      (73728)
//   EB     @ 172032           : [aa=20][16] bf16                     (640)
__global__ __launch_bounds__(256)
void prep_kernel(const float* __restrict__ W1_0, const float* __restrict__ b1_0,
                 const float* __restrict__ W1_1, const float* __restrict__ b1_1,
                 const float* __restrict__ W1_2, const float* __restrict__ b1_2,
                 const float* __restrict__ W2_0, const float* __restrict__ W2_1,
                 const float* __restrict__ W2_2,
                 const float* __restrict__ emb, char* __restrict__ ws,
                 float* __restrict__ out)
{
    const int tid = blockIdx.x * 256 + threadIdx.x;
    const int np  = gridDim.x * 256;
    if (blockIdx.x == 0 && threadIdx.x < 128) out[threadIdx.x] = 0.0f;

    // W2^T: OUTPUT-indexed -> coalesced writes; strided reads are L2-cached
    unsigned short* d2 = (unsigned short*)ws;
    for (int o = tid; o < 3 * 16384; o += np) {
        int t = o >> 14, r = o & 16383, col = r >> 7, k = r & 127;
        const float* W2 = (t == 0) ? W2_0 : (t == 1) ? W2_1 : W2_2;
        d2[o] = f2bf(W2[k * 128 + col]);
    }
    // W1^T header layout: k0=len(t0), k1=cos_t(t1), k2=sin_p(t2), k3=cos_p(t2),
    // k4=b1, k16+j = embedding row j
    unsigned short* d1 = (unsigned short*)(ws + 98304);
    for (int o = tid; o < 3 * 12288; o += np) {
        int t = o / 12288, r = o - t * 12288, hid = r / 96, k = r - hid * 96;
        const int NE16 = (t == 0) ? 32 : (t == 1) ? 48 : 64;
        const int NG   = (t == 2) ? 2 : 1;
        const float* W1 = (t == 0) ? W1_0 : (t == 1) ? W1_1 : W1_2;
        const float* b1 = (t == 0) ? b1_0 : (t == 1) ? b1_1 : b1_2;
        float v = 0.0f;
        if (k >= 16) {
            int j = k - 16;
            if (j < NE16) v = W1[(NG + j) * 128 + hid];
        } else if (k == 4) v = b1[hid];
        else if (t == 0 && k == 0) v = W1_0[hid];
        else if (t == 1 && k == 1) v = W1_1[hid];
        else if (t == 2 && k == 2) v = W1_2[hid];
        else if (t == 2 && k == 3) v = W1_2[128 + hid];
        d1[o] = f2bf(v);
    }
    unsigned short* eb = (unsigned short*)(ws + 172032);
    for (int i = tid; i < 320; i += np) eb[i] = f2bf(emb[i]);
}

struct SMem {
    unsigned short H1s[128 * SHs];  // 34816 B
    float  Rbuf[393];               // 131 rows x 3
    uint2  geomh[128];              // pre-packed bf16 header per row
    int    seqb[132];
    unsigned short ebuf[320];       // [20][16] bf16
    float  part[4];
};

template<int TYPE>
__device__ __forceinline__ void body(
    SMem& sm, const float* __restrict__ R, const int* __restrict__ seq,
    const char* __restrict__ ws,
    const float* __restrict__ b2, const float* __restrict__ w3,
    const float* __restrict__ b3, float* __restrict__ out)
{
    constexpr int NEMB  = (TYPE == 0) ? 2 : (TYPE == 1) ? 3 : 4;
    constexpr int KS    = (TYPE == 2) ? 3 : 2;
    constexpr int ROWSB = Lc - 1 - TYPE;

    const int tid = threadIdx.x;
    const int b   = blockIdx.y;
    const int i0  = blockIdx.x * 128;
    const int lane = tid & 63, wv = tid >> 6;
    const int q = lane >> 4, c = lane & 15;

    const unsigned short* w1t = (const unsigned short*)(ws + 98304 + TYPE * 24576);
    const unsigned short* w2t = (const unsigned short*)(ws + TYPE * 32768);

    // ---- stage R / seq / ebuf ----
    for (int t = tid; t < 393; t += 256) {
        int lr = t / 3, comp = t - lr * 3;
        int row = min(i0 + lr, Lc - 1);
        sm.Rbuf[t] = R[((size_t)b * Lc + row) * 3 + comp];
    }
    for (int t = tid; t < 131; t += 256)
        sm.seqb[t] = seq[b * Lc + min(i0 + t, Lc - 1)];
    {
        const uint4* se = (const uint4*)(ws + 172032);
        for (int t = tid; t < 40; t += 256) ((uint4*)sm.ebuf)[t] = se[t];
    }
    __syncthreads();

    // ---- geometry -> packed bf16 header ----
    if (tid < 128) {
        const float* p0 = &sm.Rbuf[tid * 3];
        float ax = p0[3] - p0[0], ay = p0[4] - p0[1], az = p0[5] - p0[2];
        float bx = p0[6] - p0[3], by = p0[7] - p0[4], bz = p0[8] - p0[5];
        float cx = p0[9] - p0[6], cy = p0[10] - p0[7], cz = p0[11] - p0[8];
        float na2 = ax * ax + ay * ay + az * az;
        float len = sqrtf(na2);
        float nb2 = bx * bx + by * by + bz * bz;
        float duv = -(ax * bx + ay * by + az * bz);
        float cost = fminf(fmaxf(duv / sqrtf(na2 * nb2), -1.0f), 1.0f);
        float n1x = ay * bz - az * by, n1y = az * bx - ax * bz, n1z = ax * by - ay * bx;
        float n2x = by * cz - bz * cy, n2y = bz * cx - bx * cz, n2z = bx * cy - by * cx;
        float binv = 1.0f / sqrtf(nb2);
        float ux = bx * binv, uy = by * binv, uz = bz * binv;
        float m1x = n1y * uz - n1z * uy, m1y = n1z * ux - n1x * uz, m1z = n1x * uy - n1y * ux;
        float yv = m1x * n2x + m1y * n2y + m1z * n2z;
        float xv = n1x * n2x + n1y * n2y + n1z * n2z;
        float inv = 1.0f / sqrtf(xv * xv + yv * yv);
        sm.geomh[tid] = make_uint2(pkbf(len, cost), pkbf(yv * inv, xv * inv));
    }
    __syncthreads();

    // ---- GEMM1 (swapped): D[hid][row]; B-frags gathered directly ----
    FragU A1[2][KS];
#pragma unroll
    for (int mt = 0; mt < 2; ++mt)
#pragma unroll
        for (int ks = 0; ks < KS; ++ks)
            A1[mt][ks].u = *(const uint4*)&w1t[(wv * 32 + mt * 16 + c) * 96 + ks * 32 + q * 8];

    f32x4 acc1[2][8];
#pragma unroll
    for (int mt = 0; mt < 2; ++mt)
#pragma unroll
        for (int nt = 0; nt < 8; ++nt)
            acc1[mt][nt] = (f32x4){0.f, 0.f, 0.f, 0.f};

#pragma unroll
    for (int ks = 0; ks < KS; ++ks) {
        const int k0 = ks * 32 + q * 8;
        const int j = (k0 - 16) >> 4, off = (k0 - 16) & 15;
#pragma unroll
        for (int nt = 0; nt < 8; ++nt) {
            const int m = nt * 16 + c;
            FragU bb;
            if (ks == 0 && q == 0) {                 // header [len,cos_t,sin,cos,1,0,0,0]
                uint2 g = sm.geomh[m];
                bb.u = make_uint4(g.x, g.y, 0x00003F80u, 0u);
            } else if (k0 >= 16 && j < NEMB) {       // embedding slice
                bb.u = *(const uint4*)&sm.ebuf[sm.seqb[m + j] * 16 + off];
            } else {
                bb.u = make_uint4(0u, 0u, 0u, 0u);
            }
            acc1[0][nt] = __builtin_amdgcn_mfma_f32_16x16x32_bf16(A1[0][ks].v, bb.v, acc1[0][nt], 0, 0, 0);
            acc1[1][nt] = __builtin_amdgcn_mfma_f32_16x16x32_bf16(A1[1][ks].v, bb.v, acc1[1][nt], 0, 0, 0);
        }
    }

    // ---- H1 = relu -> H1s (packed 8B writes; bias/geom already in acc) ----
    const f32x4 z4 = (f32x4){0.f, 0.f, 0.f, 0.f};
#pragma unroll
    for (int mt = 0; mt < 2; ++mt)
#pragma unroll
        for (int nt = 0; nt < 8; ++nt) {
            f32x4 v = __builtin_elementwise_max(acc1[mt][nt], z4);
            uint2 pk;
            pk.x = pkbf(v[0], v[1]);
            pk.y = pkbf(v[2], v[3]);
            *(uint2*)&sm.H1s[(nt * 16 + c) * SHs + wv * 32 + mt * 16 + q * 4] = pk;
        }

    // W2 frags + epilogue consts (issued before barrier -> latency overlapped)
    FragU B2[2][4];
#pragma unroll
    for (int nt = 0; nt < 2; ++nt)
#pragma unroll
        for (int ks = 0; ks < 4; ++ks)
            B2[nt][ks].u = *(const uint4*)&w2t[(wv * 32 + nt * 16 + c) * 128 + ks * 32 + q * 8];
    float b2v[2], w3v[2];
#pragma unroll
    for (int nt = 0; nt < 2; ++nt) {
        int col2 = wv * 32 + nt * 16 + c;
        b2v[nt] = b2[col2]; w3v[nt] = w3[col2];
    }
    __syncthreads();

    // ---- GEMM2: D[row][col2] ----
    f32x4 acc2[8][2];
#pragma unroll
    for (int mt = 0; mt < 8; ++mt)
#pragma unroll
        for (int nt = 0; nt < 2; ++nt)
            acc2[mt][nt] = (f32x4){0.f, 0.f, 0.f, 0.f};
#pragma unroll
    for (int ks = 0; ks < 4; ++ks)
#pragma unroll
        for (int mt = 0; mt < 8; ++mt) {
            bf16x8 aa = *(const bf16x8*)&sm.H1s[(mt * 16 + c) * SHs + ks * 32 + q * 8];
            acc2[mt][0] = __builtin_amdgcn_mfma_f32_16x16x32_bf16(aa, B2[0][ks].v, acc2[mt][0], 0, 0, 0);
            acc2[mt][1] = __builtin_amdgcn_mfma_f32_16x16x32_bf16(aa, B2[1][ks].v, acc2[mt][1], 0, 0, 0);
        }

    // ---- epilogue: p += relu(h2 + b2) * w3 (prefix row-mask fast path) ----
    f32x4 p4 = z4;
#pragma unroll
    for (int mt = 0; mt < 8; ++mt) {
        int mbase = mt * 16 + q * 4;
        if (i0 + mbase + 3 < ROWSB) {
#pragma unroll
            for (int nt = 0; nt < 2; ++nt) {
                f32x4 v = acc2[mt][nt] + b2v[nt];
                v = __builtin_elementwise_max(v, z4);
                p4 += v * w3v[nt];
            }
        } else {
#pragma unroll
            for (int rg = 0; rg < 4; ++rg)
                if (i0 + mbase + rg < ROWSB) {
                    p4[rg] += fmaxf(acc2[mt][0][rg] + b2v[0], 0.f) * w3v[0];
                    p4[rg] += fmaxf(acc2[mt][1][rg] + b2v[1], 0.f) * w3v[1];
                }
        }
    }
    float p = p4[0] + p4[1] + p4[2] + p4[3];
#pragma unroll
    for (int off = 32; off > 0; off >>= 1)
        p += __shfl_down(p, off);
    if (lane == 0) sm.part[wv] = p;
    __syncthreads();
    if (tid == 0) {
        int vc = min(ROWSB - i0, 128);
        atomicAdd(&out[b], sm.part[0] + sm.part[1] + sm.part[2] + sm.part[3]
                           + b3[0] * (float)vc);
    }
}

__global__ __launch_bounds__(256, 4)
void energy_kernel(const float* __restrict__ R, const int* __restrict__ seq,
                   const char* __restrict__ ws,
                   const float* b2_0, const float* b2_1, const float* b2_2,
                   const float* w3_0, const float* w3_1, const float* w3_2,
                   const float* b3_0, const float* b3_1, const float* b3_2,
                   float* __restrict__ out)
{
    __shared__ SMem sm;
    if (blockIdx.z == 0)
        body<0>(sm, R, seq, ws, b2_0, w3_0, b3_0, out);
    else if (blockIdx.z == 1)
        body<1>(sm, R, seq, ws, b2_1, w3_1, b3_1, out);
    else
        body<2>(sm, R, seq, ws, b2_2, w3_2, b3_2, out);
}

extern "C" void kernel_launch(void* const* d_in, const int* in_sizes, int n_in,
                              void* d_out, int out_size, void* d_ws, size_t ws_size,
                              hipStream_t stream) {
    const float* R   = (const float*)d_in[0];
    const int*   seq = (const int*)d_in[1];
    const float* emb = (const float*)d_in[2];
    float* out = (float*)d_out;
    char*  ws  = (char*)d_ws;

    prep_kernel<<<dim3(96), dim3(256), 0, stream>>>(
        (const float*)d_in[3],  (const float*)d_in[4],
        (const float*)d_in[9],  (const float*)d_in[10],
        (const float*)d_in[15], (const float*)d_in[16],
        (const float*)d_in[5],  (const float*)d_in[11], (const float*)d_in[17],
        emb, ws, out);

    dim3 grid(16, 128, 3), block(256);
    energy_kernel<<<grid, block, 0, stream>>>(
        R, seq, ws,
        (const float*)d_in[6],  (const float*)d_in[12], (const float*)d_in[18],
        (const float*)d_in[7],  (const float*)d_in[13], (const float*)d_in[19],
        (const float*)d_in[8],  (const float*)d_in[14], (const float*)d_in[20],
        out);
}

// Round 8
// 165.653 us; speedup vs baseline: 1.1708x; 1.0122x over previous
//
#include <hip/hip_runtime.h>

// LocalEnergy R8: one block = 128-row tile x all 3 types, processed in two
// 64-row halves (halved accumulator state -> 4 waves/SIMD; H1s = 64 rows ->
// 21 KB LDS). Geometry+bias folded into MFMA K-slots via packed bf16 header;
// direct ebuf gather; weights register-resident from prepped bf16 ws.
// B=128, L=2048, E=16, H=128. Out = 128 f32.

typedef short bf16x8 __attribute__((ext_vector_type(8)));
typedef float f32x4  __attribute__((ext_vector_type(4)));

constexpr int Lc  = 2048;
constexpr int SHs = 136;   // H1s stride (shorts) = 272 B

union FragU { uint4 u; bf16x8 v; };

__device__ __forceinline__ unsigned short f2bf(float f) {
    union { float f; unsigned u; } v; v.f = f;
    unsigned u = v.u;
    u = u + 0x7FFFu + ((u >> 16) & 1u);   // RTNE
    return (unsigned short)(u >> 16);
}

__device__ __forceinline__ unsigned pkbf(float a, float b) {
    unsigned ua = __float_as_uint(a) + 0x8000u;
    unsigned ub = __float_as_uint(b) + 0x8000u;
    return __builtin_amdgcn_perm(ub, ua, 0x07060302u);  // [lo=bf(a), hi=bf(b)]
}

// ws layout (bytes):
//   W2T[t] @ t*32768          : [col2=128][k=128] bf16 k-contig      (98304)
//   W1T[t] @ 98304 + t*24576  : [hid=128][k=96]   bf16 k-contig      (73728)
//   EB     @ 172032           : [aa=20][16] bf16                     (640)
__global__ __launch_bounds__(256)
void prep_kernel(const float* __restrict__ W1_0, const float* __restrict__ b1_0,
                 const float* __restrict__ W1_1, const float* __restrict__ b1_1,
                 const float* __restrict__ W1_2, const float* __restrict__ b1_2,
                 const float* __restrict__ W2_0, const float* __restrict__ W2_1,
                 const float* __restrict__ W2_2,
                 const float* __restrict__ emb, char* __restrict__ ws,
                 float* __restrict__ out)
{
    const int tid = blockIdx.x * 256 + threadIdx.x;
    const int np  = gridDim.x * 256;
    if (blockIdx.x == 0 && threadIdx.x < 128) out[threadIdx.x] = 0.0f;

    unsigned short* d2 = (unsigned short*)ws;
    for (int o = tid; o < 3 * 16384; o += np) {
        int t = o >> 14, r = o & 16383, col = r >> 7, k = r & 127;
        const float* W2 = (t == 0) ? W2_0 : (t == 1) ? W2_1 : W2_2;
        d2[o] = f2bf(W2[k * 128 + col]);
    }
    // W1^T header: k0=len(t0), k1=cos_t(t1), k2=sin_p(t2), k3=cos_p(t2),
    // k4=b1, k16+j = embedding row j
    unsigned short* d1 = (unsigned short*)(ws + 98304);
    for (int o = tid; o < 3 * 12288; o += np) {
        int t = o / 12288, r = o - t * 12288, hid = r / 96, k = r - hid * 96;
        const int NE16 = (t == 0) ? 32 : (t == 1) ? 48 : 64;
        const int NG   = (t == 2) ? 2 : 1;
        const float* W1 = (t == 0) ? W1_0 : (t == 1) ? W1_1 : W1_2;
        const float* b1 = (t == 0) ? b1_0 : (t == 1) ? b1_1 : b1_2;
        float v = 0.0f;
        if (k >= 16) {
            int j = k - 16;
            if (j < NE16) v = W1[(NG + j) * 128 + hid];
        } else if (k == 4) v = b1[hid];
        else if (t == 0 && k == 0) v = W1_0[hid];
        else if (t == 1 && k == 1) v = W1_1[hid];
        else if (t == 2 && k == 2) v = W1_2[hid];
        else if (t == 2 && k == 3) v = W1_2[128 + hid];
        d1[o] = f2bf(v);
    }
    unsigned short* eb = (unsigned short*)(ws + 172032);
    for (int i = tid; i < 320; i += np) eb[i] = f2bf(emb[i]);
}

struct SMem {
    unsigned short H1s[64 * SHs];   // 17408 B (one 64-row half at a time)
    float  Rbuf[393];               // 131 rows x 3
    uint2  geomh[128];              // packed bf16 header per row
    int    seqb[132];
    unsigned short ebuf[320];       // [20][16] bf16
    float  part[4];
};

// One (type, half) pass: GEMM1 over 64 rows -> H1s -> GEMM2 -> partial dot.
template<int TYPE, int H>
__device__ __forceinline__ void half_pass(
    SMem& sm, const char* __restrict__ ws,
    const float* __restrict__ b2, const float* __restrict__ w3,
    int i0, int wv, int q, int c, f32x4& p4)
{
    constexpr int NEMB  = (TYPE == 0) ? 2 : (TYPE == 1) ? 3 : 4;
    constexpr int KS    = (TYPE == 2) ? 3 : 2;
    constexpr int ROWSB = Lc - 1 - TYPE;

    const unsigned short* w1t = (const unsigned short*)(ws + 98304 + TYPE * 24576);
    const unsigned short* w2t = (const unsigned short*)(ws + TYPE * 32768);

    // GEMM1 A-frags (W1T, L2-hot; reloaded per pass to cap live registers)
    FragU A1[2][3];
#pragma unroll
    for (int mt = 0; mt < 2; ++mt)
#pragma unroll
        for (int ks = 0; ks < KS; ++ks)
            A1[mt][ks].u = *(const uint4*)&w1t[(wv * 32 + mt * 16 + c) * 96 + ks * 32 + q * 8];

    // GEMM1 (swapped): D[hid][row] for rows [H*64, H*64+64)
    f32x4 acc1[2][4];
#pragma unroll
    for (int mt = 0; mt < 2; ++mt)
#pragma unroll
        for (int nt = 0; nt < 4; ++nt)
            acc1[mt][nt] = (f32x4){0.f, 0.f, 0.f, 0.f};

#pragma unroll
    for (int ks = 0; ks < KS; ++ks) {
        const int k0 = ks * 32 + q * 8;
        const int j = (k0 - 16) >> 4, off = (k0 - 16) & 15;
#pragma unroll
        for (int nt = 0; nt < 4; ++nt) {
            const int m = H * 64 + nt * 16 + c;
            FragU bb;
            if (ks == 0 && q == 0) {                 // [len,cos_t,sin_p,cos_p,1,0,0,0]
                uint2 g = sm.geomh[m];
                bb.u = make_uint4(g.x, g.y, 0x00003F80u, 0u);
            } else if (k0 >= 16 && j < NEMB) {       // embedding slice
                bb.u = *(const uint4*)&sm.ebuf[sm.seqb[m + j] * 16 + off];
            } else {
                bb.u = make_uint4(0u, 0u, 0u, 0u);
            }
            acc1[0][nt] = __builtin_amdgcn_mfma_f32_16x16x32_bf16(A1[0][ks].v, bb.v, acc1[0][nt], 0, 0, 0);
            acc1[1][nt] = __builtin_amdgcn_mfma_f32_16x16x32_bf16(A1[1][ks].v, bb.v, acc1[1][nt], 0, 0, 0);
        }
    }

    // H1 = relu -> H1s (row-local index; bias/geom already folded via MFMA)
    const f32x4 z4 = (f32x4){0.f, 0.f, 0.f, 0.f};
#pragma unroll
    for (int mt = 0; mt < 2; ++mt)
#pragma unroll
        for (int nt = 0; nt < 4; ++nt) {
            f32x4 v = __builtin_elementwise_max(acc1[mt][nt], z4);
            uint2 pk;
            pk.x = pkbf(v[0], v[1]);
            pk.y = pkbf(v[2], v[3]);
            *(uint2*)&sm.H1s[(nt * 16 + c) * SHs + wv * 32 + mt * 16 + q * 4] = pk;
        }

    // W2 frags + epilogue consts before the barrier (latency overlapped)
    FragU B2[2][4];
#pragma unroll
    for (int nt = 0; nt < 2; ++nt)
#pragma unroll
        for (int ks = 0; ks < 4; ++ks)
            B2[nt][ks].u = *(const uint4*)&w2t[(wv * 32 + nt * 16 + c) * 128 + ks * 32 + q * 8];
    float b2v[2], w3v[2];
#pragma unroll
    for (int nt = 0; nt < 2; ++nt) {
        int col2 = wv * 32 + nt * 16 + c;
        b2v[nt] = b2[col2]; w3v[nt] = w3[col2];
    }
    __syncthreads();   // H1s ready

    // GEMM2: D[row][col2] over the 64-row half
    f32x4 acc2[4][2];
#pragma unroll
    for (int mt = 0; mt < 4; ++mt)
#pragma unroll
        for (int nt = 0; nt < 2; ++nt)
            acc2[mt][nt] = (f32x4){0.f, 0.f, 0.f, 0.f};
#pragma unroll
    for (int ks = 0; ks < 4; ++ks)
#pragma unroll
        for (int mt = 0; mt < 4; ++mt) {
            bf16x8 aa = *(const bf16x8*)&sm.H1s[(mt * 16 + c) * SHs + ks * 32 + q * 8];
            acc2[mt][0] = __builtin_amdgcn_mfma_f32_16x16x32_bf16(aa, B2[0][ks].v, acc2[mt][0], 0, 0, 0);
            acc2[mt][1] = __builtin_amdgcn_mfma_f32_16x16x32_bf16(aa, B2[1][ks].v, acc2[mt][1], 0, 0, 0);
        }

    // epilogue: p4 += relu(h2 + b2) * w3 (prefix row-mask fast path)
#pragma unroll
    for (int mt = 0; mt < 4; ++mt) {
        int mbase = H * 64 + mt * 16 + q * 4;
        if (i0 + mbase + 3 < ROWSB) {
#pragma unroll
            for (int nt = 0; nt < 2; ++nt) {
                f32x4 v = acc2[mt][nt] + b2v[nt];
                v = __builtin_elementwise_max(v, z4);
                p4 += v * w3v[nt];
            }
        } else {
#pragma unroll
            for (int rg = 0; rg < 4; ++rg)
                if (i0 + mbase + rg < ROWSB) {
                    p4[rg] += fmaxf(acc2[mt][0][rg] + b2v[0], 0.f) * w3v[0];
                    p4[rg] += fmaxf(acc2[mt][1][rg] + b2v[1], 0.f) * w3v[1];
                }
        }
    }
    __syncthreads();   // protect H1s before the next pass overwrites
}

__global__ __launch_bounds__(256, 4)
void energy_kernel(const float* __restrict__ R, const int* __restrict__ seq,
                   const char* __restrict__ ws,
                   const float* b2_0, const float* b2_1, const float* b2_2,
                   const float* w3_0, const float* w3_1, const float* w3_2,
                   const float* b3_0, const float* b3_1, const float* b3_2,
                   float* __restrict__ out)
{
    __shared__ SMem sm;
    const int tid = threadIdx.x;
    const int b   = blockIdx.y;
    const int i0  = blockIdx.x * 128;
    const int lane = tid & 63, wv = tid >> 6;
    const int q = lane >> 4, c = lane & 15;

    // ---- stage R / seq / ebuf (once for all 3 types) ----
    for (int t = tid; t < 393; t += 256) {
        int lr = t / 3, comp = t - lr * 3;
        int row = min(i0 + lr, Lc - 1);
        sm.Rbuf[t] = R[((size_t)b * Lc + row) * 3 + comp];
    }
    for (int t = tid; t < 131; t += 256)
        sm.seqb[t] = seq[b * Lc + min(i0 + t, Lc - 1)];
    {
        const uint4* se = (const uint4*)(ws + 172032);
        for (int t = tid; t < 40; t += 256) ((uint4*)sm.ebuf)[t] = se[t];
    }
    __syncthreads();

    // ---- geometry -> packed bf16 header (once) ----
    if (tid < 128) {
        const float* p0 = &sm.Rbuf[tid * 3];
        float ax = p0[3] - p0[0], ay = p0[4] - p0[1], az = p0[5] - p0[2];
        float bx = p0[6] - p0[3], by = p0[7] - p0[4], bz = p0[8] - p0[5];
        float cx = p0[9] - p0[6], cy = p0[10] - p0[7], cz = p0[11] - p0[8];
        float na2 = ax * ax + ay * ay + az * az;
        float len = sqrtf(na2);
        float nb2 = bx * bx + by * by + bz * bz;
        float duv = -(ax * bx + ay * by + az * bz);
        float cost = fminf(fmaxf(duv / sqrtf(na2 * nb2), -1.0f), 1.0f);
        float n1x = ay * bz - az * by, n1y = az * bx - ax * bz, n1z = ax * by - ay * bx;
        float n2x = by * cz - bz * cy, n2y = bz * cx - bx * cz, n2z = bx * cy - by * cx;
        float binv = 1.0f / sqrtf(nb2);
        float ux = bx * binv, uy = by * binv, uz = bz * binv;
        float m1x = n1y * uz - n1z * uy, m1y = n1z * ux - n1x * uz, m1z = n1x * uy - n1y * ux;
        float yv = m1x * n2x + m1y * n2y + m1z * n2z;
        float xv = n1x * n2x + n1y * n2y + n1z * n2z;
        float inv = 1.0f / sqrtf(xv * xv + yv * yv);
        sm.geomh[tid] = make_uint2(pkbf(len, cost), pkbf(yv * inv, xv * inv));
    }
    __syncthreads();

    // ---- six (type, half) passes sharing staged data ----
    f32x4 p4 = (f32x4){0.f, 0.f, 0.f, 0.f};
    half_pass<0, 0>(sm, ws, b2_0, w3_0, i0, wv, q, c, p4);
    half_pass<0, 1>(sm, ws, b2_0, w3_0, i0, wv, q, c, p4);
    half_pass<1, 0>(sm, ws, b2_1, w3_1, i0, wv, q, c, p4);
    half_pass<1, 1>(sm, ws, b2_1, w3_1, i0, wv, q, c, p4);
    half_pass<2, 0>(sm, ws, b2_2, w3_2, i0, wv, q, c, p4);
    half_pass<2, 1>(sm, ws, b2_2, w3_2, i0, wv, q, c, p4);

    float p = p4[0] + p4[1] + p4[2] + p4[3];
#pragma unroll
    for (int off = 32; off > 0; off >>= 1)
        p += __shfl_down(p, off);
    if (lane == 0) sm.part[wv] = p;
    __syncthreads();
    if (tid == 0) {
        float tot = sm.part[0] + sm.part[1] + sm.part[2] + sm.part[3];
        tot += b3_0[0] * (float)min(Lc - 1 - i0, 128);
        tot += b3_1[0] * (float)min(Lc - 2 - i0, 128);
        tot += b3_2[0] * (float)min(Lc - 3 - i0, 128);
        atomicAdd(&out[b], tot);
    }
}

extern "C" void kernel_launch(void* const* d_in, const int* in_sizes, int n_in,
                              void* d_out, int out_size, void* d_ws, size_t ws_size,
                              hipStream_t stream) {
    const float* R   = (const float*)d_in[0];
    const int*   seq = (const int*)d_in[1];
    const float* emb = (const float*)d_in[2];
    float* out = (float*)d_out;
    char*  ws  = (char*)d_ws;

    prep_kernel<<<dim3(96), dim3(256), 0, stream>>>(
        (const float*)d_in[3],  (const float*)d_in[4],
        (const float*)d_in[9],  (const float*)d_in[10],
        (const float*)d_in[15], (const float*)d_in[16],
        (const float*)d_in[5],  (const float*)d_in[11], (const float*)d_in[17],
        emb, ws, out);

    dim3 grid(16, 128), block(256);
    energy_kernel<<<grid, block, 0, stream>>>(
        R, seq, ws,
        (const float*)d_in[6],  (const float*)d_in[12], (const float*)d_in[18],
        (const float*)d_in[7],  (const float*)d_in[13], (const float*)d_in[19],
        (const float*)d_in[8],  (const float*)d_in[14], (const float*)d_in[20],
        out);
}